// Round 5
// baseline (671.674 us; speedup 1.0000x reference)
//
#include <hip/hip_runtime.h>

#define T_SEQ 512
#define U_TAGS 128
#define D_DIM 1024
#define M_ROWS (64 * T_SEQ)  // 32768

// ---------------------------------------------------------------------------
// Kernel 1a: partial GEMM over K-slice. grid = (256 m-tiles, nparts) blocks.
// launch_bounds(256,4) caps VGPR at 128 (8x8 micro needs ~111) -> 4 waves/SIMD
// actually resident with 1024 blocks -> latency hiding (round-3 failure: 1
// wave/SIMD exposed every ds_read->fma chain).
// ---------------------------------------------------------------------------
__global__ __launch_bounds__(256, 4) void crf_gemm_part(
    const float* __restrict__ A, const float* __restrict__ Bk,
    float* __restrict__ Cpart, int kdepth) {
  __shared__ float As[16][132];
  __shared__ float Bs[16][132];
  const int tid = threadIdx.x;
  const int tx = tid & 15, ty = tid >> 4;
  const int row0 = blockIdx.x * 128;
  const int kbase = blockIdx.y * kdepth;

  const int am = tid >> 2, ak = (tid & 3) << 2;
  const int bk = tid >> 5, bn = (tid & 31) << 2;

  float acc[8][8] = {};

  float4 a0 = *(const float4*)&A[(size_t)(row0 + am) * D_DIM + kbase + ak];
  float4 a1 = *(const float4*)&A[(size_t)(row0 + am + 64) * D_DIM + kbase + ak];
  float4 b0 = *(const float4*)&Bk[(size_t)(kbase + bk) * U_TAGS + bn];
  float4 b1 = *(const float4*)&Bk[(size_t)(kbase + bk + 8) * U_TAGS + bn];

  for (int k0 = 0; k0 < kdepth; k0 += 16) {
    As[ak + 0][am] = a0.x; As[ak + 1][am] = a0.y;
    As[ak + 2][am] = a0.z; As[ak + 3][am] = a0.w;
    As[ak + 0][am + 64] = a1.x; As[ak + 1][am + 64] = a1.y;
    As[ak + 2][am + 64] = a1.z; As[ak + 3][am + 64] = a1.w;
    *(float4*)&Bs[bk][bn] = b0;
    *(float4*)&Bs[bk + 8][bn] = b1;
    __syncthreads();
    if (k0 + 16 < kdepth) {
      const int kn = kbase + k0 + 16;
      a0 = *(const float4*)&A[(size_t)(row0 + am) * D_DIM + kn + ak];
      a1 = *(const float4*)&A[(size_t)(row0 + am + 64) * D_DIM + kn + ak];
      b0 = *(const float4*)&Bk[(size_t)(kn + bk) * U_TAGS + bn];
      b1 = *(const float4*)&Bk[(size_t)(kn + bk + 8) * U_TAGS + bn];
    }
#pragma unroll
    for (int kk = 0; kk < 16; ++kk) {
      float a[8], b[8];
      *(float4*)&a[0] = *(const float4*)&As[kk][ty * 8];
      *(float4*)&a[4] = *(const float4*)&As[kk][ty * 8 + 4];
      *(float4*)&b[0] = *(const float4*)&Bs[kk][tx * 4];
      *(float4*)&b[4] = *(const float4*)&Bs[kk][tx * 4 + 64];
#pragma unroll
      for (int r = 0; r < 8; ++r)
#pragma unroll
        for (int c = 0; c < 8; ++c) acc[r][c] = fmaf(a[r], b[c], acc[r][c]);
    }
    __syncthreads();
  }

  float* Cp = Cpart + (size_t)blockIdx.y * M_ROWS * U_TAGS;
#pragma unroll
  for (int r = 0; r < 8; ++r) {
    const int row = row0 + ty * 8 + r;
    *(float4*)&Cp[(size_t)row * U_TAGS + tx * 4] = *(float4*)&acc[r][0];
    *(float4*)&Cp[(size_t)row * U_TAGS + tx * 4 + 64] = *(float4*)&acc[r][4];
  }
}

// ---------------------------------------------------------------------------
// Kernel 1b: logits = sum(parts, ascending) + bias (+boundaries), in place
// over part 0. Fixed order -> bitwise deterministic.
// ---------------------------------------------------------------------------
__global__ __launch_bounds__(256) void crf_combine(
    float* __restrict__ p, const float* __restrict__ bias,
    const float* __restrict__ lb, const float* __restrict__ rb, int nparts) {
  const int i = blockIdx.x * 256 + threadIdx.x;  // float4 index
  const int row = i >> 5;
  const int col = (i & 31) << 2;
  const int t = row & (T_SEQ - 1);
  float4 o = *(const float4*)&p[(size_t)i * 4];
  for (int q = 1; q < nparts; ++q) {
    const float* pq = p + (size_t)q * M_ROWS * U_TAGS;
    float4 v = *(const float4*)&pq[(size_t)i * 4];
    o.x += v.x; o.y += v.y; o.z += v.z; o.w += v.w;
  }
  float4 bb = *(const float4*)&bias[col];
  o.x += bb.x; o.y += bb.y; o.z += bb.z; o.w += bb.w;
  if (t == 0) {
    float4 l = *(const float4*)&lb[col];
    o.x += l.x; o.y += l.y; o.z += l.z; o.w += l.w;
  }
  if (t == T_SEQ - 1) {
    float4 r = *(const float4*)&rb[col];
    o.x += r.x; o.y += r.y; o.z += r.z; o.w += r.w;
  }
  *(float4*)&p[(size_t)i * 4] = o;
}

// ---------------------------------------------------------------------------
// Fallback single-K GEMM (only if ws too small for splits). Round-3 proven.
// ---------------------------------------------------------------------------
__global__ __launch_bounds__(256) void crf_gemm(
    const float* __restrict__ A, const float* __restrict__ Bk,
    const float* __restrict__ bias, const float* __restrict__ lb,
    const float* __restrict__ rb, float* __restrict__ C) {
  __shared__ float As[16][132];
  __shared__ float Bs[16][132];
  const int tid = threadIdx.x;
  const int tx = tid & 15, ty = tid >> 4;
  const int row0 = blockIdx.x * 128;
  const int am = tid >> 2, ak = (tid & 3) << 2;
  const int bk = tid >> 5, bn = (tid & 31) << 2;
  float acc[8][8] = {};
  float4 a0 = *(const float4*)&A[(size_t)(row0 + am) * D_DIM + ak];
  float4 a1 = *(const float4*)&A[(size_t)(row0 + am + 64) * D_DIM + ak];
  float4 b0 = *(const float4*)&Bk[(size_t)bk * U_TAGS + bn];
  float4 b1 = *(const float4*)&Bk[(size_t)(bk + 8) * U_TAGS + bn];
  for (int k0 = 0; k0 < D_DIM; k0 += 16) {
    As[ak + 0][am] = a0.x; As[ak + 1][am] = a0.y;
    As[ak + 2][am] = a0.z; As[ak + 3][am] = a0.w;
    As[ak + 0][am + 64] = a1.x; As[ak + 1][am + 64] = a1.y;
    As[ak + 2][am + 64] = a1.z; As[ak + 3][am + 64] = a1.w;
    *(float4*)&Bs[bk][bn] = b0;
    *(float4*)&Bs[bk + 8][bn] = b1;
    __syncthreads();
    if (k0 + 16 < D_DIM) {
      a0 = *(const float4*)&A[(size_t)(row0 + am) * D_DIM + k0 + 16 + ak];
      a1 = *(const float4*)&A[(size_t)(row0 + am + 64) * D_DIM + k0 + 16 + ak];
      b0 = *(const float4*)&Bk[(size_t)(k0 + 16 + bk) * U_TAGS + bn];
      b1 = *(const float4*)&Bk[(size_t)(k0 + 16 + bk + 8) * U_TAGS + bn];
    }
#pragma unroll
    for (int kk = 0; kk < 16; ++kk) {
      float a[8], b[8];
      *(float4*)&a[0] = *(const float4*)&As[kk][ty * 8];
      *(float4*)&a[4] = *(const float4*)&As[kk][ty * 8 + 4];
      *(float4*)&b[0] = *(const float4*)&Bs[kk][tx * 4];
      *(float4*)&b[4] = *(const float4*)&Bs[kk][tx * 4 + 64];
#pragma unroll
      for (int r = 0; r < 8; ++r)
#pragma unroll
        for (int c = 0; c < 8; ++c) acc[r][c] = fmaf(a[r], b[c], acc[r][c]);
    }
    __syncthreads();
  }
#pragma unroll
  for (int r = 0; r < 8; ++r) {
    const int row = row0 + ty * 8 + r;
    const int t = row & (T_SEQ - 1);
    const int n0 = tx * 4, n1 = tx * 4 + 64;
    float o[8];
#pragma unroll
    for (int c = 0; c < 4; ++c) {
      float v = acc[r][c] + bias[n0 + c];
      if (t == 0) v += lb[n0 + c];
      if (t == T_SEQ - 1) v += rb[n0 + c];
      o[c] = v;
    }
#pragma unroll
    for (int c = 0; c < 4; ++c) {
      float v = acc[r][c + 4] + bias[n1 + c];
      if (t == 0) v += lb[n1 + c];
      if (t == T_SEQ - 1) v += rb[n1 + c];
      o[c + 4] = v;
    }
    *(float4*)&C[(size_t)row * U_TAGS + n0] = *(float4*)&o[0];
    *(float4*)&C[(size_t)row * U_TAGS + n1] = *(float4*)&o[4];
  }
}

// ---------------------------------------------------------------------------
// Kernel 2: Viterbi with candidate pruning.
// One block (256 thr) per batch; wave 0 runs the whole forward recurrence
// barrier-free: v[128] lives in 2 VGPRs/lane (v0@lane, v1@lane+64).
// Per step: vm = wave-max (DPP reduce), candidates = {i : v[i]+rowmax_tr[i]
// >= vm + gmin - margin} (sound superset of all argmax winners; typ. 2-5 of
// 128), found via ballot + scalar ctz. Scores computed with the exact same
// fp32 adds as the reference -> bitwise-identical v trajectory; ascending-i
// strict-> processing preserves first-index tie semantics.
// ---------------------------------------------------------------------------
__device__ __forceinline__ float rl_f(float v, int lane) {
  return __int_as_float(__builtin_amdgcn_readlane(__float_as_int(v), lane));
}
template <int CTRL>
__device__ __forceinline__ float dpp_max_step(float x) {
  int v = __float_as_int(x);
  int t = __builtin_amdgcn_update_dpp(v, v, CTRL, 0xF, 0xF, false);
  return fmaxf(x, __int_as_float(t));
}
__device__ __forceinline__ float wave_max64_bcast(float x) {
  x = dpp_max_step<0x111>(x);  // row_shr:1
  x = dpp_max_step<0x112>(x);  // row_shr:2
  x = dpp_max_step<0x114>(x);  // row_shr:4
  x = dpp_max_step<0x118>(x);  // row_shr:8
  x = dpp_max_step<0x142>(x);  // row_bcast:15
  x = dpp_max_step<0x143>(x);  // row_bcast:31
  return rl_f(x, 63);          // full-wave max, uniform
}

__global__ __launch_bounds__(256) void crf_viterbi(
    const float* __restrict__ logits,  // [64, 512, 128]
    const float* __restrict__ trans,   // [128, 128]
    float* __restrict__ out) {         // [64, 512] fp32 tags
  __shared__ __align__(16) float trs[U_TAGS * U_TAGS];         // 64 KB
  __shared__ __align__(16) unsigned char bp[(T_SEQ - 1) * U_TAGS];  // 65408 B
  __shared__ unsigned char tags[T_SEQ];
  __shared__ unsigned char M[8][U_TAGS];
  __shared__ float rmaxs[U_TAGS];
  __shared__ float wmin2[2];
  __shared__ float gminS;
  __shared__ int lastTagS;

  const int b = blockIdx.x;
  const int tid = threadIdx.x;
  const float* lg_b = logits + (size_t)b * T_SEQ * U_TAGS;

  // Stage trans (coalesced), 16 float4 per thread.
#pragma unroll
  for (int it = 0; it < 16; ++it)
    *(float4*)&trs[(it * 256 + tid) * 4] =
        *(const float4*)&trans[(it * 256 + tid) * 4];
  __syncthreads();

  // Per-row max (rmaxs[i] = max_j trs[i][j]) and global min of trans.
  float rowmin = 1e30f;
  if (tid < U_TAGS) {
    float mx = -1e30f, mn = 1e30f;
    for (int q = 0; q < 32; ++q) {
      float4 v = *(const float4*)&trs[tid * U_TAGS + q * 4];
      mx = fmaxf(fmaxf(mx, v.x), fmaxf(v.y, fmaxf(v.z, v.w)));
      mn = fminf(fminf(mn, v.x), fminf(v.y, fminf(v.z, v.w)));
    }
    rmaxs[tid] = mx;
    rowmin = mn;
  }
  if (tid < U_TAGS) {
#pragma unroll
    for (int off = 1; off < 64; off <<= 1)
      rowmin = fminf(rowmin, __shfl_xor(rowmin, off));
    if ((tid & 63) == 0) wmin2[tid >> 6] = rowmin;
  }
  __syncthreads();
  if (tid == 0) gminS = fminf(wmin2[0], wmin2[1]);
  __syncthreads();

  if (tid < 64) {  // wave 0: the entire forward recurrence, barrier-free
    const int l = tid;
    float v0 = lg_b[l];            // t=0 (lb fused by GEMM)
    float v1 = lg_b[64 + l];
    const float gmin = gminS;
    const float c0 = rmaxs[l] - gmin + 0.01f;        // margin 0.01 >> fp32 err
    const float c1 = rmaxs[64 + l] - gmin + 0.01f;
    // logit prefetch pipeline (2 deep)
    float lgA0 = lg_b[U_TAGS + l], lgA1 = lg_b[U_TAGS + 64 + l];
    float lgB0 = lg_b[2 * U_TAGS + l], lgB1 = lg_b[2 * U_TAGS + 64 + l];

    for (int t = 1; t < T_SEQ; ++t) {
      int tp = t + 2; if (tp > T_SEQ - 1) tp = T_SEQ - 1;
      float lgC0 = lg_b[(size_t)tp * U_TAGS + l];
      float lgC1 = lg_b[(size_t)tp * U_TAGS + 64 + l];

      const float vm = wave_max64_bcast(fmaxf(v0, v1));
      unsigned long long m0 = __ballot(v0 + c0 >= vm);
      unsigned long long m1 = __ballot(v1 + c1 >= vm);

      // extract up to 2 slots per mask (uniform scalars)
      int a0 = -1, a1 = -1, b0 = -1, b1 = -1;
      if (m0) { a0 = __builtin_ctzll(m0); m0 &= m0 - 1;
        if (m0) { a1 = __builtin_ctzll(m0); m0 &= m0 - 1; } }
      if (m1) { b0 = __builtin_ctzll(m1); m1 &= m1 - 1;
        if (m1) { b1 = __builtin_ctzll(m1); m1 &= m1 - 1; } }

      // issue all slot LDS reads up front (latency overlap)
      float tA00 = 0, tA01 = 0, tA10 = 0, tA11 = 0;
      float tB00 = 0, tB01 = 0, tB10 = 0, tB11 = 0;
      if (a0 >= 0) { tA00 = trs[a0 * U_TAGS + l]; tA01 = trs[a0 * U_TAGS + 64 + l]; }
      if (a1 >= 0) { tA10 = trs[a1 * U_TAGS + l]; tA11 = trs[a1 * U_TAGS + 64 + l]; }
      if (b0 >= 0) { tB00 = trs[(64 + b0) * U_TAGS + l]; tB01 = trs[(64 + b0) * U_TAGS + 64 + l]; }
      if (b1 >= 0) { tB10 = trs[(64 + b1) * U_TAGS + l]; tB11 = trs[(64 + b1) * U_TAGS + 64 + l]; }

      float best0 = -1e30f, best1 = -1e30f;
      int bi0 = 0, bi1 = 0;
      // process ascending i with strict > (first-index tie semantics)
      if (a0 >= 0) {
        float vi = rl_f(v0, a0);
        float s0 = vi + tA00, s1 = vi + tA01;
        if (s0 > best0) { best0 = s0; bi0 = a0; }
        if (s1 > best1) { best1 = s1; bi1 = a0; }
      }
      if (a1 >= 0) {
        float vi = rl_f(v0, a1);
        float s0 = vi + tA10, s1 = vi + tA11;
        if (s0 > best0) { best0 = s0; bi0 = a1; }
        if (s1 > best1) { best1 = s1; bi1 = a1; }
      }
      while (m0) {  // rare overflow tail, still ascending
        int i = __builtin_ctzll(m0); m0 &= m0 - 1;
        float vi = rl_f(v0, i);
        float s0 = vi + trs[i * U_TAGS + l], s1 = vi + trs[i * U_TAGS + 64 + l];
        if (s0 > best0) { best0 = s0; bi0 = i; }
        if (s1 > best1) { best1 = s1; bi1 = i; }
      }
      if (b0 >= 0) {
        float vi = rl_f(v1, b0);
        float s0 = vi + tB00, s1 = vi + tB01;
        if (s0 > best0) { best0 = s0; bi0 = 64 + b0; }
        if (s1 > best1) { best1 = s1; bi1 = 64 + b0; }
      }
      if (b1 >= 0) {
        float vi = rl_f(v1, b1);
        float s0 = vi + tB10, s1 = vi + tB11;
        if (s0 > best0) { best0 = s0; bi0 = 64 + b1; }
        if (s1 > best1) { best1 = s1; bi1 = 64 + b1; }
      }
      while (m1) {
        int i = __builtin_ctzll(m1); m1 &= m1 - 1;
        float vi = rl_f(v1, i);
        float s0 = vi + trs[(64 + i) * U_TAGS + l];
        float s1 = vi + trs[(64 + i) * U_TAGS + 64 + l];
        if (s0 > best0) { best0 = s0; bi0 = 64 + i; }
        if (s1 > best1) { best1 = s1; bi1 = 64 + i; }
      }

      bp[(t - 1) * U_TAGS + l] = (unsigned char)bi0;
      bp[(t - 1) * U_TAGS + 64 + l] = (unsigned char)bi1;
      v0 = best0 + lgA0;   // same fp32 ops as reference
      v1 = best1 + lgA1;
      lgA0 = lgB0; lgA1 = lgB1;
      lgB0 = lgC0; lgB1 = lgC1;
    }

    // final argmax (first max over j=0..127)
    float val = v0; int idx = l;
    if (v1 > v0) { val = v1; idx = 64 + l; }
#pragma unroll
    for (int off = 1; off < 64; off <<= 1) {
      float vo = __shfl_xor(val, off);
      int io = __shfl_xor(idx, off);
      if (vo > val || (vo == val && io < idx)) { val = vo; idx = io; }
    }
    if (l == 0) { lastTagS = idx; tags[T_SEQ - 1] = (unsigned char)idx; }
  }
  __syncthreads();  // waves 1-3 waited here during the forward pass

  // Backtrack pass A: 1024 chains (8 chunks x 128 seeds), 4 per thread.
#pragma unroll
  for (int q = 0; q < 4; ++q) {
    const int chain = tid + q * 256;
    const int c = chain >> 7, s = chain & 127;
    const int lo = c * 64;
    const int hi = (c == 7) ? (T_SEQ - 2) : (c * 64 + 63);
    int cur = s;
    for (int t = hi; t >= lo; --t) cur = bp[t * U_TAGS + cur];
    M[c][s] = (unsigned char)cur;
  }
  __syncthreads();
  __shared__ unsigned char seedE[8];
  if (tid == 0) {
    int e = lastTagS;           // tag at t=511 (= entry of chunk 7)
    seedE[7] = (unsigned char)e;
    for (int c = 7; c >= 1; --c) { e = M[c][e]; seedE[c - 1] = (unsigned char)e; }
  }
  __syncthreads();
  // Pass B: 8 threads re-walk their chunk writing tags.
  if (tid < 8) {
    const int c = tid;
    const int lo = c * 64;
    const int hi = (c == 7) ? (T_SEQ - 2) : (c * 64 + 63);
    int cur = seedE[c];
    for (int t = hi; t >= lo; --t) {
      cur = bp[t * U_TAGS + cur];
      tags[t] = (unsigned char)cur;
    }
  }
  __syncthreads();
  out[(size_t)b * T_SEQ + tid] = (float)tags[tid];
  out[(size_t)b * T_SEQ + 256 + tid] = (float)tags[256 + tid];
}

// ---------------------------------------------------------------------------
extern "C" void kernel_launch(void* const* d_in, const int* in_sizes, int n_in,
                              void* d_out, int out_size, void* d_ws,
                              size_t ws_size, hipStream_t stream) {
  const float* x = (const float*)d_in[0];
  const float* kern = (const float*)d_in[1];
  const float* bias = (const float*)d_in[2];
  const float* chain = (const float*)d_in[3];
  const float* lb = (const float*)d_in[4];
  const float* rb = (const float*)d_in[5];
  float* out = (float*)d_out;
  float* logits = (float*)d_ws;  // final logits at ws base in all paths

  const size_t part = (size_t)M_ROWS * U_TAGS * sizeof(float);  // 16.8 MB
  const int nblk = M_ROWS * U_TAGS / 4 / 256;                   // combine grid
  if (ws_size >= 4 * part) {
    crf_gemm_part<<<dim3(256, 4), 256, 0, stream>>>(x, kern, logits, D_DIM / 4);
    crf_combine<<<nblk, 256, 0, stream>>>(logits, bias, lb, rb, 4);
  } else if (ws_size >= 2 * part) {
    crf_gemm_part<<<dim3(256, 2), 256, 0, stream>>>(x, kern, logits, D_DIM / 2);
    crf_combine<<<nblk, 256, 0, stream>>>(logits, bias, lb, rb, 2);
  } else {
    crf_gemm<<<256, 256, 0, stream>>>(x, kern, bias, lb, rb, logits);
  }
  crf_viterbi<<<64, 256, 0, stream>>>(logits, chain, out);
}

// Round 6
// 667.994 us; speedup vs baseline: 1.0055x; 1.0055x over previous
//
#include <hip/hip_runtime.h>

#define T_SEQ 512
#define U_TAGS 128
#define D_DIM 1024
#define M_ROWS (64 * T_SEQ)  // 32768

// ---------------------------------------------------------------------------
// Kernel 1a: partial GEMM over K-slice. 128-thread blocks, 64m x 128n tile,
// 8x8 micro (B/FMA = 1.0, LDS-pipe floor 82 us). Grid (512 m-tiles, 4 K) =
// 2048 blocks -> 8 blocks/CU -> ~4 waves/SIMD naturally (VGPR ~110, no
// launch-bound cap: round-5's forced cap spilled and regressed).
// ---------------------------------------------------------------------------
__global__ __launch_bounds__(128) void crf_gemm_part(
    const float* __restrict__ A, const float* __restrict__ Bk,
    float* __restrict__ Cpart, int kdepth) {
  __shared__ float As[16][68];   // [k][m], +4 pad
  __shared__ float Bs[16][132];  // [k][n], +4 pad
  const int tid = threadIdx.x;
  const int tx = tid & 15, ty = tid >> 4;  // 16 x 8
  const int row0 = blockIdx.x * 64;
  const int kbase = blockIdx.y * kdepth;

  const int am = tid >> 1, ak = (tid & 1) << 3;  // A: 64m x 16k, 2 f4/thread
  const int bk0 = tid >> 5, bn = (tid & 31) << 2;  // B: 16k x 128n, 4 f4/thread

  float acc[8][8] = {};

  float4 a0 = *(const float4*)&A[(size_t)(row0 + am) * D_DIM + kbase + ak];
  float4 a1 = *(const float4*)&A[(size_t)(row0 + am) * D_DIM + kbase + ak + 4];
  float4 b0 = *(const float4*)&Bk[(size_t)(kbase + bk0) * U_TAGS + bn];
  float4 b1 = *(const float4*)&Bk[(size_t)(kbase + bk0 + 4) * U_TAGS + bn];
  float4 b2 = *(const float4*)&Bk[(size_t)(kbase + bk0 + 8) * U_TAGS + bn];
  float4 b3 = *(const float4*)&Bk[(size_t)(kbase + bk0 + 12) * U_TAGS + bn];

  for (int k0 = 0; k0 < kdepth; k0 += 16) {
    As[ak + 0][am] = a0.x; As[ak + 1][am] = a0.y;
    As[ak + 2][am] = a0.z; As[ak + 3][am] = a0.w;
    As[ak + 4][am] = a1.x; As[ak + 5][am] = a1.y;
    As[ak + 6][am] = a1.z; As[ak + 7][am] = a1.w;
    *(float4*)&Bs[bk0][bn] = b0;
    *(float4*)&Bs[bk0 + 4][bn] = b1;
    *(float4*)&Bs[bk0 + 8][bn] = b2;
    *(float4*)&Bs[bk0 + 12][bn] = b3;
    __syncthreads();
    if (k0 + 16 < kdepth) {
      const int kn = kbase + k0 + 16;
      a0 = *(const float4*)&A[(size_t)(row0 + am) * D_DIM + kn + ak];
      a1 = *(const float4*)&A[(size_t)(row0 + am) * D_DIM + kn + ak + 4];
      b0 = *(const float4*)&Bk[(size_t)(kn + bk0) * U_TAGS + bn];
      b1 = *(const float4*)&Bk[(size_t)(kn + bk0 + 4) * U_TAGS + bn];
      b2 = *(const float4*)&Bk[(size_t)(kn + bk0 + 8) * U_TAGS + bn];
      b3 = *(const float4*)&Bk[(size_t)(kn + bk0 + 12) * U_TAGS + bn];
    }
#pragma unroll
    for (int kk = 0; kk < 16; ++kk) {
      float a[8], b[8];
      *(float4*)&a[0] = *(const float4*)&As[kk][ty * 8];        // bcast x16
      *(float4*)&a[4] = *(const float4*)&As[kk][ty * 8 + 4];
      *(float4*)&b[0] = *(const float4*)&Bs[kk][tx * 4];        // 2-way, free
      *(float4*)&b[4] = *(const float4*)&Bs[kk][tx * 4 + 64];   // 2-way, free
#pragma unroll
      for (int r = 0; r < 8; ++r)
#pragma unroll
        for (int c = 0; c < 8; ++c) acc[r][c] = fmaf(a[r], b[c], acc[r][c]);
    }
    __syncthreads();
  }

  float* Cp = Cpart + (size_t)blockIdx.y * M_ROWS * U_TAGS;
#pragma unroll
  for (int r = 0; r < 8; ++r) {
    const int row = row0 + ty * 8 + r;
    *(float4*)&Cp[(size_t)row * U_TAGS + tx * 4] = *(float4*)&acc[r][0];
    *(float4*)&Cp[(size_t)row * U_TAGS + tx * 4 + 64] = *(float4*)&acc[r][4];
  }
}

// ---------------------------------------------------------------------------
// Kernel 1b: logits = sum(parts, ascending) + bias (+boundaries), in place
// over part 0. Fixed order -> bitwise deterministic.
// ---------------------------------------------------------------------------
__global__ __launch_bounds__(256) void crf_combine(
    float* __restrict__ p, const float* __restrict__ bias,
    const float* __restrict__ lb, const float* __restrict__ rb, int nparts) {
  const int i = blockIdx.x * 256 + threadIdx.x;  // float4 index
  const int row = i >> 5;
  const int col = (i & 31) << 2;
  const int t = row & (T_SEQ - 1);
  float4 o = *(const float4*)&p[(size_t)i * 4];
  for (int q = 1; q < nparts; ++q) {
    const float* pq = p + (size_t)q * M_ROWS * U_TAGS;
    float4 v = *(const float4*)&pq[(size_t)i * 4];
    o.x += v.x; o.y += v.y; o.z += v.z; o.w += v.w;
  }
  float4 bb = *(const float4*)&bias[col];
  o.x += bb.x; o.y += bb.y; o.z += bb.z; o.w += bb.w;
  if (t == 0) {
    float4 l = *(const float4*)&lb[col];
    o.x += l.x; o.y += l.y; o.z += l.z; o.w += l.w;
  }
  if (t == T_SEQ - 1) {
    float4 r = *(const float4*)&rb[col];
    o.x += r.x; o.y += r.y; o.z += r.z; o.w += r.w;
  }
  *(float4*)&p[(size_t)i * 4] = o;
}

// ---------------------------------------------------------------------------
// Fallback single-K GEMM (only if ws too small for splits).
// ---------------------------------------------------------------------------
__global__ __launch_bounds__(256) void crf_gemm(
    const float* __restrict__ A, const float* __restrict__ Bk,
    const float* __restrict__ bias, const float* __restrict__ lb,
    const float* __restrict__ rb, float* __restrict__ C) {
  __shared__ float As[16][132];
  __shared__ float Bs[16][132];
  const int tid = threadIdx.x;
  const int tx = tid & 15, ty = tid >> 4;
  const int row0 = blockIdx.x * 128;
  const int am = tid >> 2, ak = (tid & 3) << 2;
  const int bk = tid >> 5, bn = (tid & 31) << 2;
  float acc[8][8] = {};
  float4 a0 = *(const float4*)&A[(size_t)(row0 + am) * D_DIM + ak];
  float4 a1 = *(const float4*)&A[(size_t)(row0 + am + 64) * D_DIM + ak];
  float4 b0 = *(const float4*)&Bk[(size_t)bk * U_TAGS + bn];
  float4 b1 = *(const float4*)&Bk[(size_t)(bk + 8) * U_TAGS + bn];
  for (int k0 = 0; k0 < D_DIM; k0 += 16) {
    As[ak + 0][am] = a0.x; As[ak + 1][am] = a0.y;
    As[ak + 2][am] = a0.z; As[ak + 3][am] = a0.w;
    As[ak + 0][am + 64] = a1.x; As[ak + 1][am + 64] = a1.y;
    As[ak + 2][am + 64] = a1.z; As[ak + 3][am + 64] = a1.w;
    *(float4*)&Bs[bk][bn] = b0;
    *(float4*)&Bs[bk + 8][bn] = b1;
    __syncthreads();
    if (k0 + 16 < D_DIM) {
      a0 = *(const float4*)&A[(size_t)(row0 + am) * D_DIM + k0 + 16 + ak];
      a1 = *(const float4*)&A[(size_t)(row0 + am + 64) * D_DIM + k0 + 16 + ak];
      b0 = *(const float4*)&Bk[(size_t)(k0 + 16 + bk) * U_TAGS + bn];
      b1 = *(const float4*)&Bk[(size_t)(k0 + 16 + bk + 8) * U_TAGS + bn];
    }
#pragma unroll
    for (int kk = 0; kk < 16; ++kk) {
      float a[8], b[8];
      *(float4*)&a[0] = *(const float4*)&As[kk][ty * 8];
      *(float4*)&a[4] = *(const float4*)&As[kk][ty * 8 + 4];
      *(float4*)&b[0] = *(const float4*)&Bs[kk][tx * 4];
      *(float4*)&b[4] = *(const float4*)&Bs[kk][tx * 4 + 64];
#pragma unroll
      for (int r = 0; r < 8; ++r)
#pragma unroll
        for (int c = 0; c < 8; ++c) acc[r][c] = fmaf(a[r], b[c], acc[r][c]);
    }
    __syncthreads();
  }
#pragma unroll
  for (int r = 0; r < 8; ++r) {
    const int row = row0 + ty * 8 + r;
    const int t = row & (T_SEQ - 1);
    const int n0 = tx * 4, n1 = tx * 4 + 64;
    float o[8];
#pragma unroll
    for (int c = 0; c < 4; ++c) {
      float v = acc[r][c] + bias[n0 + c];
      if (t == 0) v += lb[n0 + c];
      if (t == T_SEQ - 1) v += rb[n0 + c];
      o[c] = v;
    }
#pragma unroll
    for (int c = 0; c < 4; ++c) {
      float v = acc[r][c + 4] + bias[n1 + c];
      if (t == 0) v += lb[n1 + c];
      if (t == T_SEQ - 1) v += rb[n1 + c];
      o[c + 4] = v;
    }
    *(float4*)&C[(size_t)row * U_TAGS + n0] = *(float4*)&o[0];
    *(float4*)&C[(size_t)row * U_TAGS + n1] = *(float4*)&o[4];
  }
}

// ---------------------------------------------------------------------------
// Kernel 2: Viterbi, pruned + BRANCHLESS step.
// Round-5 failure: exec-mask branches (if/while per slot) cost ~1200 cyc/step.
// Now: fixed 4+4 slots, SALU-only extraction (ctz on mask|1<<63, validity ->
// score -1e30), all 16 trans LDS reads issued unconditionally, winner via
// first-index-stable cndmask tree. Rare >8-candidate tail = one untaken
// branch with tie-aware compare.
// ---------------------------------------------------------------------------
__device__ __forceinline__ float rl_f(float v, int lane) {
  return __int_as_float(__builtin_amdgcn_readlane(__float_as_int(v), lane));
}
template <int CTRL>
__device__ __forceinline__ float dpp_max_step(float x) {
  int v = __float_as_int(x);
  int t = __builtin_amdgcn_update_dpp(v, v, CTRL, 0xF, 0xF, false);
  return fmaxf(x, __int_as_float(t));
}
__device__ __forceinline__ float wave_max64_bcast(float x) {
  x = dpp_max_step<0x111>(x);  // row_shr:1
  x = dpp_max_step<0x112>(x);  // row_shr:2
  x = dpp_max_step<0x114>(x);  // row_shr:4
  x = dpp_max_step<0x118>(x);  // row_shr:8
  x = dpp_max_step<0x142>(x);  // row_bcast:15
  x = dpp_max_step<0x143>(x);  // row_bcast:31
  return rl_f(x, 63);          // exact full-wave max (sound for pruning)
}
// winner select: a must carry the smaller candidate index; ties keep a.
__device__ __forceinline__ void win(float sa, int ia, float sb, int ib,
                                    float& so, int& io) {
  bool g = sa >= sb;
  so = g ? sa : sb;
  io = g ? ia : ib;
}

__global__ __launch_bounds__(256) void crf_viterbi(
    const float* __restrict__ logits,  // [64, 512, 128]
    const float* __restrict__ trans,   // [128, 128]
    float* __restrict__ out) {         // [64, 512] fp32 tags
  __shared__ __align__(16) float trs[U_TAGS * U_TAGS];              // 64 KB
  __shared__ __align__(16) unsigned char bp[(T_SEQ - 1) * U_TAGS];  // 65408 B
  __shared__ unsigned char tags[T_SEQ];
  __shared__ unsigned char M[8][U_TAGS];
  __shared__ float rmaxs[U_TAGS];
  __shared__ float wmin2[2];
  __shared__ float gminS;
  __shared__ int lastTagS;

  const int b = blockIdx.x;
  const int tid = threadIdx.x;
  const float* lg_b = logits + (size_t)b * T_SEQ * U_TAGS;

  // Stage trans (coalesced), 16 float4 per thread.
#pragma unroll
  for (int it = 0; it < 16; ++it)
    *(float4*)&trs[(it * 256 + tid) * 4] =
        *(const float4*)&trans[(it * 256 + tid) * 4];
  __syncthreads();

  // rmaxs[i] = max_j trs[i][j]; gmin = min over all trans.
  float rowmin = 1e30f;
  if (tid < U_TAGS) {
    float mx = -1e30f, mn = 1e30f;
    for (int q = 0; q < 32; ++q) {
      float4 v = *(const float4*)&trs[tid * U_TAGS + q * 4];
      mx = fmaxf(fmaxf(mx, v.x), fmaxf(v.y, fmaxf(v.z, v.w)));
      mn = fminf(fminf(mn, v.x), fminf(v.y, fminf(v.z, v.w)));
    }
    rmaxs[tid] = mx;
    rowmin = mn;
  }
  if (tid < U_TAGS) {
#pragma unroll
    for (int off = 1; off < 64; off <<= 1)
      rowmin = fminf(rowmin, __shfl_xor(rowmin, off));
    if ((tid & 63) == 0) wmin2[tid >> 6] = rowmin;
  }
  __syncthreads();
  if (tid == 0) gminS = fminf(wmin2[0], wmin2[1]);
  __syncthreads();

  if (tid < 64) {  // wave 0: entire forward recurrence, barrier-free
    const int l = tid;
    float v0 = lg_b[l];  // t=0 (lb fused upstream)
    float v1 = lg_b[64 + l];
    const float gmin = gminS;
    const float c0 = rmaxs[l] - gmin + 0.01f;  // margin >> fp32 rounding
    const float c1 = rmaxs[64 + l] - gmin + 0.01f;
    float lgA0 = lg_b[U_TAGS + l], lgA1 = lg_b[U_TAGS + 64 + l];
    float lgB0 = lg_b[2 * U_TAGS + l], lgB1 = lg_b[2 * U_TAGS + 64 + l];

    for (int t = 1; t < T_SEQ; ++t) {
      int tp = t + 2; if (tp > T_SEQ - 1) tp = T_SEQ - 1;
      float lgC0 = lg_b[(size_t)tp * U_TAGS + l];
      float lgC1 = lg_b[(size_t)tp * U_TAGS + 64 + l];

      const float vm = wave_max64_bcast(fmaxf(v0, v1));
      unsigned long long m0 = __ballot(v0 + c0 >= vm);
      unsigned long long m1 = __ballot(v1 + c1 >= vm);

      // Branchless extraction: 4 slots per half (SALU only).
      unsigned long long r0 = m0, r1 = m1;
      int i0[4], i1[4];
      bool f0[4], f1[4];
#pragma unroll
      for (int s = 0; s < 4; ++s) {
        f0[s] = (r0 != 0ull);
        i0[s] = __builtin_ctzll(r0 | 0x8000000000000000ull);
        r0 &= r0 - 1;
        f1[s] = (r1 != 0ull);
        i1[s] = __builtin_ctzll(r1 | 0x8000000000000000ull);
        r1 &= r1 - 1;
      }
      // Scalar v values, gated to -inf when slot invalid.
      float sv0[4], sv1[4];
#pragma unroll
      for (int s = 0; s < 4; ++s) {
        sv0[s] = f0[s] ? rl_f(v0, i0[s]) : -1e30f;
        sv1[s] = f1[s] ? rl_f(v1, i1[s]) : -1e30f;
      }
      // All 16 LDS reads issued unconditionally.
      float tA[4][2], tB[4][2];
#pragma unroll
      for (int s = 0; s < 4; ++s) {
        const float* pA = &trs[i0[s] * U_TAGS + l];
        tA[s][0] = pA[0]; tA[s][1] = pA[64];
        const float* pB = &trs[(64 + i1[s]) * U_TAGS + l];
        tB[s][0] = pB[0]; tB[s][1] = pB[64];
      }
      // Scores for j=l (L) and j=64+l (H).
      float sAL[4], sAH[4], sBL[4], sBH[4];
#pragma unroll
      for (int s = 0; s < 4; ++s) {
        sAL[s] = sv0[s] + tA[s][0]; sAH[s] = sv0[s] + tA[s][1];
        sBL[s] = sv1[s] + tB[s][0]; sBH[s] = sv1[s] + tB[s][1];
      }
      // Winner trees (slot order ascending-index; A-group before B-group).
      float wL, wL2, wL3, wL4, wH, wH2, wH3, wH4;
      int xL, xL2, xL3, xL4, xH, xH2, xH3, xH4;
      win(sAL[0], i0[0], sAL[1], i0[1], wL, xL);
      win(sAL[2], i0[2], sAL[3], i0[3], wL2, xL2);
      win(sBL[0], 64 + i1[0], sBL[1], 64 + i1[1], wL3, xL3);
      win(sBL[2], 64 + i1[2], sBL[3], 64 + i1[3], wL4, xL4);
      win(wL, xL, wL2, xL2, wL, xL);
      win(wL3, xL3, wL4, xL4, wL3, xL3);
      win(wL, xL, wL3, xL3, wL, xL);
      win(sAH[0], i0[0], sAH[1], i0[1], wH, xH);
      win(sAH[2], i0[2], sAH[3], i0[3], wH2, xH2);
      win(sBH[0], 64 + i1[0], sBH[1], 64 + i1[1], wH3, xH3);
      win(sBH[2], 64 + i1[2], sBH[3], 64 + i1[3], wH4, xH4);
      win(wH, xH, wH2, xH2, wH, xH);
      win(wH3, xH3, wH4, xH4, wH3, xH3);
      win(wH, xH, wH3, xH3, wH, xH);

      // Rare tail (>4 candidates in a half): tie-aware (first-index) compare.
      if (r0 | r1) {
        while (r0) {
          int i = __builtin_ctzll(r0); r0 &= r0 - 1;
          float vi = rl_f(v0, i);
          float sL = vi + trs[i * U_TAGS + l];
          float sH = vi + trs[i * U_TAGS + 64 + l];
          if (sL > wL || (sL == wL && i < xL)) { wL = sL; xL = i; }
          if (sH > wH || (sH == wH && i < xH)) { wH = sH; xH = i; }
        }
        while (r1) {
          int i = __builtin_ctzll(r1); r1 &= r1 - 1;
          float vi = rl_f(v1, i);
          float sL = vi + trs[(64 + i) * U_TAGS + l];
          float sH = vi + trs[(64 + i) * U_TAGS + 64 + l];
          if (sL > wL || (sL == wL && 64 + i < xL)) { wL = sL; xL = 64 + i; }
          if (sH > wH || (sH == wH && 64 + i < xH)) { wH = sH; xH = 64 + i; }
        }
      }

      bp[(t - 1) * U_TAGS + l] = (unsigned char)xL;
      bp[(t - 1) * U_TAGS + 64 + l] = (unsigned char)xH;
      v0 = wL + lgA0;  // same fp32 ops as reference
      v1 = wH + lgA1;
      lgA0 = lgB0; lgA1 = lgB1;
      lgB0 = lgC0; lgB1 = lgC1;
    }

    // final argmax (first max over j=0..127)
    float val = v0; int idx = l;
    if (v1 > v0) { val = v1; idx = 64 + l; }
#pragma unroll
    for (int off = 1; off < 64; off <<= 1) {
      float vo = __shfl_xor(val, off);
      int io = __shfl_xor(idx, off);
      if (vo > val || (vo == val && io < idx)) { val = vo; idx = io; }
    }
    if (l == 0) { lastTagS = idx; tags[T_SEQ - 1] = (unsigned char)idx; }
  }
  __syncthreads();  // waves 1-3 waited here during the forward pass

  // Backtrack pass A: 1024 chains (8 chunks x 128 seeds), 4 per thread.
#pragma unroll
  for (int q = 0; q < 4; ++q) {
    const int chain = tid + q * 256;
    const int c = chain >> 7, s = chain & 127;
    const int lo = c * 64;
    const int hi = (c == 7) ? (T_SEQ - 2) : (c * 64 + 63);
    int cur = s;
    for (int t = hi; t >= lo; --t) cur = bp[t * U_TAGS + cur];
    M[c][s] = (unsigned char)cur;
  }
  __syncthreads();
  __shared__ unsigned char seedE[8];
  if (tid == 0) {
    int e = lastTagS;
    seedE[7] = (unsigned char)e;
    for (int c = 7; c >= 1; --c) { e = M[c][e]; seedE[c - 1] = (unsigned char)e; }
  }
  __syncthreads();
  if (tid < 8) {
    const int c = tid;
    const int lo = c * 64;
    const int hi = (c == 7) ? (T_SEQ - 2) : (c * 64 + 63);
    int cur = seedE[c];
    for (int t = hi; t >= lo; --t) {
      cur = bp[t * U_TAGS + cur];
      tags[t] = (unsigned char)cur;
    }
  }
  __syncthreads();
  out[(size_t)b * T_SEQ + tid] = (float)tags[tid];
  out[(size_t)b * T_SEQ + 256 + tid] = (float)tags[256 + tid];
}

// ---------------------------------------------------------------------------
extern "C" void kernel_launch(void* const* d_in, const int* in_sizes, int n_in,
                              void* d_out, int out_size, void* d_ws,
                              size_t ws_size, hipStream_t stream) {
  const float* x = (const float*)d_in[0];
  const float* kern = (const float*)d_in[1];
  const float* bias = (const float*)d_in[2];
  const float* chain = (const float*)d_in[3];
  const float* lb = (const float*)d_in[4];
  const float* rb = (const float*)d_in[5];
  float* out = (float*)d_out;
  float* logits = (float*)d_ws;  // final logits at ws base in all paths

  const size_t part = (size_t)M_ROWS * U_TAGS * sizeof(float);  // 16.8 MB
  const int nblk = M_ROWS * U_TAGS / 4 / 256;                   // combine grid
  if (ws_size >= 4 * part) {
    crf_gemm_part<<<dim3(512, 4), 128, 0, stream>>>(x, kern, logits, D_DIM / 4);
    crf_combine<<<nblk, 256, 0, stream>>>(logits, bias, lb, rb, 4);
  } else if (ws_size >= 2 * part) {
    crf_gemm_part<<<dim3(512, 2), 128, 0, stream>>>(x, kern, logits, D_DIM / 2);
    crf_combine<<<nblk, 256, 0, stream>>>(logits, bias, lb, rb, 2);
  } else {
    crf_gemm<<<256, 256, 0, stream>>>(x, kern, bias, lb, rb, logits);
  }
  crf_viterbi<<<64, 256, 0, stream>>>(logits, chain, out);
}

// Round 7
// 589.729 us; speedup vs baseline: 1.1390x; 1.1327x over previous
//
#include <hip/hip_runtime.h>

#define T_SEQ 512
#define U_TAGS 128
#define D_DIM 1024
#define M_ROWS (64 * T_SEQ)  // 32768

// ---------------------------------------------------------------------------
// Kernel 1a: partial GEMM over half of K (round-3 proven config, best so far).
// 128x128 tile, 256 threads, 8x8 micro, K-tile 16, register prefetch.
// ---------------------------------------------------------------------------
__global__ __launch_bounds__(256) void crf_gemm_half(
    const float* __restrict__ A, const float* __restrict__ Bk,
    float* __restrict__ Cpart) {
  __shared__ float As[16][132];
  __shared__ float Bs[16][132];
  const int tid = threadIdx.x;
  const int tx = tid & 15, ty = tid >> 4;
  const int row0 = blockIdx.x * 128;
  const int kbase = blockIdx.y * (D_DIM / 2);

  const int am = tid >> 2, ak = (tid & 3) << 2;
  const int bk = tid >> 5, bn = (tid & 31) << 2;

  float acc[8][8] = {};

  float4 a0 = *(const float4*)&A[(size_t)(row0 + am) * D_DIM + kbase + ak];
  float4 a1 = *(const float4*)&A[(size_t)(row0 + am + 64) * D_DIM + kbase + ak];
  float4 b0 = *(const float4*)&Bk[(size_t)(kbase + bk) * U_TAGS + bn];
  float4 b1 = *(const float4*)&Bk[(size_t)(kbase + bk + 8) * U_TAGS + bn];

  for (int k0 = 0; k0 < D_DIM / 2; k0 += 16) {
    As[ak + 0][am] = a0.x; As[ak + 1][am] = a0.y;
    As[ak + 2][am] = a0.z; As[ak + 3][am] = a0.w;
    As[ak + 0][am + 64] = a1.x; As[ak + 1][am + 64] = a1.y;
    As[ak + 2][am + 64] = a1.z; As[ak + 3][am + 64] = a1.w;
    *(float4*)&Bs[bk][bn] = b0;
    *(float4*)&Bs[bk + 8][bn] = b1;
    __syncthreads();
    if (k0 + 16 < D_DIM / 2) {
      const int kn = kbase + k0 + 16;
      a0 = *(const float4*)&A[(size_t)(row0 + am) * D_DIM + kn + ak];
      a1 = *(const float4*)&A[(size_t)(row0 + am + 64) * D_DIM + kn + ak];
      b0 = *(const float4*)&Bk[(size_t)(kn + bk) * U_TAGS + bn];
      b1 = *(const float4*)&Bk[(size_t)(kn + bk + 8) * U_TAGS + bn];
    }
#pragma unroll
    for (int kk = 0; kk < 16; ++kk) {
      float a[8], b[8];
      *(float4*)&a[0] = *(const float4*)&As[kk][ty * 8];
      *(float4*)&a[4] = *(const float4*)&As[kk][ty * 8 + 4];
      *(float4*)&b[0] = *(const float4*)&Bs[kk][tx * 4];
      *(float4*)&b[4] = *(const float4*)&Bs[kk][tx * 4 + 64];
#pragma unroll
      for (int r = 0; r < 8; ++r)
#pragma unroll
        for (int c = 0; c < 8; ++c) acc[r][c] = fmaf(a[r], b[c], acc[r][c]);
    }
    __syncthreads();
  }

  float* Cp = Cpart + (size_t)blockIdx.y * M_ROWS * U_TAGS;
#pragma unroll
  for (int r = 0; r < 8; ++r) {
    const int row = row0 + ty * 8 + r;
    *(float4*)&Cp[(size_t)row * U_TAGS + tx * 4] = *(float4*)&acc[r][0];
    *(float4*)&Cp[(size_t)row * U_TAGS + tx * 4 + 64] = *(float4*)&acc[r][4];
  }
}

// ---------------------------------------------------------------------------
// Kernel 1b: logits = p0 + p1 + bias (+boundaries), in place over p0.
// ---------------------------------------------------------------------------
__global__ __launch_bounds__(256) void crf_combine(
    float* __restrict__ p, const float* __restrict__ bias,
    const float* __restrict__ lb, const float* __restrict__ rb) {
  const int i = blockIdx.x * 256 + threadIdx.x;  // float4 index
  const int row = i >> 5;
  const int col = (i & 31) << 2;
  const int t = row & (T_SEQ - 1);
  const float* p1 = p + (size_t)M_ROWS * U_TAGS;
  float4 v0 = *(const float4*)&p[(size_t)i * 4];
  float4 v1 = *(const float4*)&p1[(size_t)i * 4];
  float4 bb = *(const float4*)&bias[col];
  float4 o;
  o.x = v0.x + v1.x + bb.x; o.y = v0.y + v1.y + bb.y;
  o.z = v0.z + v1.z + bb.z; o.w = v0.w + v1.w + bb.w;
  if (t == 0) {
    float4 l = *(const float4*)&lb[col];
    o.x += l.x; o.y += l.y; o.z += l.z; o.w += l.w;
  }
  if (t == T_SEQ - 1) {
    float4 r = *(const float4*)&rb[col];
    o.x += r.x; o.y += r.y; o.z += r.z; o.w += r.w;
  }
  *(float4*)&p[(size_t)i * 4] = o;
}

// ---------------------------------------------------------------------------
// Fallback single-K GEMM (only if ws too small).
// ---------------------------------------------------------------------------
__global__ __launch_bounds__(256) void crf_gemm(
    const float* __restrict__ A, const float* __restrict__ Bk,
    const float* __restrict__ bias, const float* __restrict__ lb,
    const float* __restrict__ rb, float* __restrict__ C) {
  __shared__ float As[16][132];
  __shared__ float Bs[16][132];
  const int tid = threadIdx.x;
  const int tx = tid & 15, ty = tid >> 4;
  const int row0 = blockIdx.x * 128;
  const int am = tid >> 2, ak = (tid & 3) << 2;
  const int bk = tid >> 5, bn = (tid & 31) << 2;
  float acc[8][8] = {};
  float4 a0 = *(const float4*)&A[(size_t)(row0 + am) * D_DIM + ak];
  float4 a1 = *(const float4*)&A[(size_t)(row0 + am + 64) * D_DIM + ak];
  float4 b0 = *(const float4*)&Bk[(size_t)bk * U_TAGS + bn];
  float4 b1 = *(const float4*)&Bk[(size_t)(bk + 8) * U_TAGS + bn];
  for (int k0 = 0; k0 < D_DIM; k0 += 16) {
    As[ak + 0][am] = a0.x; As[ak + 1][am] = a0.y;
    As[ak + 2][am] = a0.z; As[ak + 3][am] = a0.w;
    As[ak + 0][am + 64] = a1.x; As[ak + 1][am + 64] = a1.y;
    As[ak + 2][am + 64] = a1.z; As[ak + 3][am + 64] = a1.w;
    *(float4*)&Bs[bk][bn] = b0;
    *(float4*)&Bs[bk + 8][bn] = b1;
    __syncthreads();
    if (k0 + 16 < D_DIM) {
      a0 = *(const float4*)&A[(size_t)(row0 + am) * D_DIM + k0 + 16 + ak];
      a1 = *(const float4*)&A[(size_t)(row0 + am + 64) * D_DIM + k0 + 16 + ak];
      b0 = *(const float4*)&Bk[(size_t)(k0 + 16 + bk) * U_TAGS + bn];
      b1 = *(const float4*)&Bk[(size_t)(k0 + 16 + bk + 8) * U_TAGS + bn];
    }
#pragma unroll
    for (int kk = 0; kk < 16; ++kk) {
      float a[8], b[8];
      *(float4*)&a[0] = *(const float4*)&As[kk][ty * 8];
      *(float4*)&a[4] = *(const float4*)&As[kk][ty * 8 + 4];
      *(float4*)&b[0] = *(const float4*)&Bs[kk][tx * 4];
      *(float4*)&b[4] = *(const float4*)&Bs[kk][tx * 4 + 64];
#pragma unroll
      for (int r = 0; r < 8; ++r)
#pragma unroll
        for (int c = 0; c < 8; ++c) acc[r][c] = fmaf(a[r], b[c], acc[r][c]);
    }
    __syncthreads();
  }
#pragma unroll
  for (int r = 0; r < 8; ++r) {
    const int row = row0 + ty * 8 + r;
    const int t = row & (T_SEQ - 1);
    const int n0 = tx * 4, n1 = tx * 4 + 64;
    float o[8];
#pragma unroll
    for (int c = 0; c < 4; ++c) {
      float v = acc[r][c] + bias[n0 + c];
      if (t == 0) v += lb[n0 + c];
      if (t == T_SEQ - 1) v += rb[n0 + c];
      o[c] = v;
    }
#pragma unroll
    for (int c = 0; c < 4; ++c) {
      float v = acc[r][c + 4] + bias[n1 + c];
      if (t == 0) v += lb[n1 + c];
      if (t == T_SEQ - 1) v += rb[n1 + c];
      o[c + 4] = v;
    }
    *(float4*)&C[(size_t)row * U_TAGS + n0] = *(float4*)&o[0];
    *(float4*)&C[(size_t)row * U_TAGS + n1] = *(float4*)&o[4];
  }
}

// ---------------------------------------------------------------------------
// Kernel 2: Viterbi, pruned, producer/consumer logit staging.
// Wave 0 = consumer: forward recurrence touching ONLY LDS (rounds 1-6 were
// bound by per-step global-logit latency ~1500 cyc). Wave 1 = producer:
// stages logits into a 4-slot x 8-step LDS ring, flow-controlled by LDS
// flags (workgroup-coherent; DS ops in-order per wave).
// Step: wave-max via DPP -> ballot prune -> 3+3 candidate slots. All slots
// resolve to REAL (i, v[i], trans-row) pairs (empty -> guard index 63 /
// dup), so no validity gating is needed: any real pair is a legitimate
// competitor under reference argmax-over-all-i semantics; ascending-index
// win tree keeps first-index ties. Rare >3/half tail: tie-aware fallback.
// ---------------------------------------------------------------------------
__device__ __forceinline__ float rl_f(float v, int lane) {
  return __int_as_float(__builtin_amdgcn_readlane(__float_as_int(v), lane));
}
template <int CTRL>
__device__ __forceinline__ float dpp_max_step(float x) {
  int v = __float_as_int(x);
  int t = __builtin_amdgcn_update_dpp(v, v, CTRL, 0xF, 0xF, false);
  return fmaxf(x, __int_as_float(t));
}
__device__ __forceinline__ float wave_max64_bcast(float x) {
  x = dpp_max_step<0x111>(x);  // row_shr:1
  x = dpp_max_step<0x112>(x);  // row_shr:2
  x = dpp_max_step<0x114>(x);  // row_shr:4
  x = dpp_max_step<0x118>(x);  // row_shr:8
  x = dpp_max_step<0x142>(x);  // row_bcast:15
  x = dpp_max_step<0x143>(x);  // row_bcast:31
  return rl_f(x, 63);
}
// keep a on ties; a must carry the smaller candidate index
__device__ __forceinline__ void win(float sa, int ia, float sb, int ib,
                                    float& so, int& io) {
  bool g = sa >= sb;
  so = g ? sa : sb;
  io = g ? ia : ib;
}

__global__ __launch_bounds__(256) void crf_viterbi(
    const float* __restrict__ logits,  // [64, 512, 128]
    const float* __restrict__ trans,   // [128, 128]
    float* __restrict__ out) {         // [64, 512] fp32 tags
  __shared__ __align__(16) float trs[U_TAGS * U_TAGS];              // 64 KB
  __shared__ __align__(16) unsigned char bp[(T_SEQ - 1) * U_TAGS];  // 65408 B
  __shared__ __align__(16) float ring[4 * 8 * U_TAGS];              // 16 KB
  __shared__ int flags[2];  // [0]=chunks produced, [1]=chunks consumed
  __shared__ unsigned char tags[T_SEQ];
  __shared__ unsigned char M[8][U_TAGS];
  __shared__ unsigned char seedE[8];
  __shared__ float rmaxs[U_TAGS];
  __shared__ float wmin2[2];
  __shared__ float gminS;
  __shared__ int lastTagS;

  const int b = blockIdx.x;
  const int tid = threadIdx.x;
  const float* lg_b = logits + (size_t)b * T_SEQ * U_TAGS;

  // Stage trans (coalesced), 16 float4 per thread.
#pragma unroll
  for (int it = 0; it < 16; ++it)
    *(float4*)&trs[(it * 256 + tid) * 4] =
        *(const float4*)&trans[(it * 256 + tid) * 4];
  if (tid == 0) { flags[0] = 0; flags[1] = 0; }
  __syncthreads();

  // rmaxs[i] = max_j trs[i][j]; gmin = min over all trans.
  float rowmin = 1e30f;
  if (tid < U_TAGS) {
    float mx = -1e30f, mn = 1e30f;
    for (int q = 0; q < 32; ++q) {
      float4 v = *(const float4*)&trs[tid * U_TAGS + q * 4];
      mx = fmaxf(fmaxf(mx, v.x), fmaxf(v.y, fmaxf(v.z, v.w)));
      mn = fminf(fminf(mn, v.x), fminf(v.y, fminf(v.z, v.w)));
    }
    rmaxs[tid] = mx;
    rowmin = mn;
#pragma unroll
    for (int off = 1; off < 64; off <<= 1)
      rowmin = fminf(rowmin, __shfl_xor(rowmin, off));
    if ((tid & 63) == 0) wmin2[tid >> 6] = rowmin;
  }
  __syncthreads();
  if (tid == 0) gminS = fminf(wmin2[0], wmin2[1]);
  __syncthreads();

  const int wv = tid >> 6, l = tid & 63;
  volatile int* vfl = (volatile int*)flags;

  if (wv == 1) {
    // ---- producer: 64 chunks x (8 steps x 128 floats = 4 KB) ----
    const float4* src = (const float4*)lg_b;
    float4* dst = (float4*)ring;
    for (int c = 0; c < 64; ++c) {
      while (vfl[1] + 4 <= c) { }  // ring credit
      const float4* s4 = src + c * 256;
      float4 d0 = s4[l], d1 = s4[l + 64], d2 = s4[l + 128], d3 = s4[l + 192];
      float4* d4 = dst + (c & 3) * 256;
      d4[l] = d0; d4[l + 64] = d1; d4[l + 128] = d2; d4[l + 192] = d3;
      __threadfence_block();
      if (l == 0) vfl[0] = c + 1;
    }
  } else if (wv == 0) {
    // ---- consumer: the whole forward recurrence, LDS-only ----
    const float cc0 = rmaxs[l] - gminS + 0.01f;
    const float cc1 = rmaxs[64 + l] - gminS + 0.01f;
    while (vfl[0] < 1) { }
    float v0 = ring[l];       // t=0 (lb fused upstream)
    float v1 = ring[64 + l];
    const unsigned long long G = 0x8000000000000000ull;
    int bpoff = l;

    for (int t = 1; t < T_SEQ; ++t) {
      if ((t & 7) == 0) {
        const int c = t >> 3;
        if (l == 0) vfl[1] = c;       // chunks < c fully consumed
        while (vfl[0] <= c) { }
      }
      const float* sl = ring + ((t >> 3) & 3) * 1024 + (t & 7) * U_TAGS;
      float lg0 = sl[l];
      float lg1 = sl[64 + l];

      const float vm = wave_max64_bcast(fmaxf(v0, v1));
      unsigned long long m0 = __ballot(v0 + cc0 >= vm);
      unsigned long long m1 = __ballot(v1 + cc1 >= vm);

      // 3 slots per half; empty/dup -> guard index 63 (a real pair).
      unsigned long long rA1 = m0 & (m0 - 1), rA2 = rA1 & (rA1 - 1);
      unsigned long long rB1 = m1 & (m1 - 1), rB2 = rB1 & (rB1 - 1);
      const int iA0 = __builtin_ctzll(m0 | G);
      const int iA1 = __builtin_ctzll(rA1 | G);
      const int iA2 = __builtin_ctzll(rA2 | G);
      const int iB0 = __builtin_ctzll(m1 | G);
      const int iB1 = __builtin_ctzll(rB1 | G);
      const int iB2 = __builtin_ctzll(rB2 | G);
      unsigned long long tail = (rA2 & (rA2 - 1)) | (rB2 & (rB2 - 1));

      const float svA0 = rl_f(v0, iA0), svA1 = rl_f(v0, iA1),
                  svA2 = rl_f(v0, iA2);
      const float svB0 = rl_f(v1, iB0), svB1 = rl_f(v1, iB1),
                  svB2 = rl_f(v1, iB2);

      const float* pA0 = &trs[iA0 * U_TAGS + l];
      const float* pA1 = &trs[iA1 * U_TAGS + l];
      const float* pA2 = &trs[iA2 * U_TAGS + l];
      const float* pB0 = &trs[(64 + iB0) * U_TAGS + l];
      const float* pB1 = &trs[(64 + iB1) * U_TAGS + l];
      const float* pB2 = &trs[(64 + iB2) * U_TAGS + l];
      const float tA0L = pA0[0], tA0H = pA0[64];
      const float tA1L = pA1[0], tA1H = pA1[64];
      const float tA2L = pA2[0], tA2H = pA2[64];
      const float tB0L = pB0[0], tB0H = pB0[64];
      const float tB1L = pB1[0], tB1H = pB1[64];
      const float tB2L = pB2[0], tB2H = pB2[64];

      // L target (j = l)
      float wa, wb, wL; int xa, xb, xL;
      win(svA0 + tA0L, iA0, svA1 + tA1L, iA1, wa, xa);
      win(wa, xa, svA2 + tA2L, iA2, wa, xa);
      win(svB0 + tB0L, 64 + iB0, svB1 + tB1L, 64 + iB1, wb, xb);
      win(wb, xb, svB2 + tB2L, 64 + iB2, wb, xb);
      win(wa, xa, wb, xb, wL, xL);
      // H target (j = 64 + l)
      float wH; int xH;
      win(svA0 + tA0H, iA0, svA1 + tA1H, iA1, wa, xa);
      win(wa, xa, svA2 + tA2H, iA2, wa, xa);
      win(svB0 + tB0H, 64 + iB0, svB1 + tB1H, 64 + iB1, wb, xb);
      win(wb, xb, svB2 + tB2H, 64 + iB2, wb, xb);
      win(wa, xa, wb, xb, wH, xH);

      if (tail) {  // rare: >3 candidates in a half, tie-aware
        unsigned long long r = rA2 & (rA2 - 1);
        while (r) {
          int i = __builtin_ctzll(r); r &= r - 1;
          float vi = rl_f(v0, i);
          float sL = vi + trs[i * U_TAGS + l];
          float sH = vi + trs[i * U_TAGS + 64 + l];
          if (sL > wL || (sL == wL && i < xL)) { wL = sL; xL = i; }
          if (sH > wH || (sH == wH && i < xH)) { wH = sH; xH = i; }
        }
        r = rB2 & (rB2 - 1);
        while (r) {
          int i = __builtin_ctzll(r); r &= r - 1;
          float vi = rl_f(v1, i);
          float sL = vi + trs[(64 + i) * U_TAGS + l];
          float sH = vi + trs[(64 + i) * U_TAGS + 64 + l];
          if (sL > wL || (sL == wL && 64 + i < xL)) { wL = sL; xL = 64 + i; }
          if (sH > wH || (sH == wH && 64 + i < xH)) { wH = sH; xH = 64 + i; }
        }
      }

      bp[bpoff] = (unsigned char)xL;
      bp[bpoff + 64] = (unsigned char)xH;
      bpoff += U_TAGS;
      v0 = wL + lg0;  // same fp32 ops as reference
      v1 = wH + lg1;
    }

    // final argmax (first max over j=0..127)
    float val = v0; int idx = l;
    if (v1 > v0) { val = v1; idx = 64 + l; }
#pragma unroll
    for (int off = 1; off < 64; off <<= 1) {
      float vo = __shfl_xor(val, off);
      int io = __shfl_xor(idx, off);
      if (vo > val || (vo == val && io < idx)) { val = vo; idx = io; }
    }
    if (l == 0) { lastTagS = idx; tags[T_SEQ - 1] = (unsigned char)idx; }
  }
  __syncthreads();  // waves 2-3 waited here during the forward pass

  // Backtrack pass A: 1024 chains (8 chunks x 128 seeds), 4 per thread.
#pragma unroll
  for (int q = 0; q < 4; ++q) {
    const int chain = tid + q * 256;
    const int c = chain >> 7, s = chain & 127;
    const int lo = c * 64;
    const int hi = (c == 7) ? (T_SEQ - 2) : (c * 64 + 63);
    int cur = s;
    for (int t = hi; t >= lo; --t) cur = bp[t * U_TAGS + cur];
    M[c][s] = (unsigned char)cur;
  }
  __syncthreads();
  if (tid == 0) {
    int e = lastTagS;
    seedE[7] = (unsigned char)e;
    for (int c = 7; c >= 1; --c) { e = M[c][e]; seedE[c - 1] = (unsigned char)e; }
  }
  __syncthreads();
  if (tid < 8) {
    const int c = tid;
    const int lo = c * 64;
    const int hi = (c == 7) ? (T_SEQ - 2) : (c * 64 + 63);
    int cur = seedE[c];
    for (int t = hi; t >= lo; --t) {
      cur = bp[t * U_TAGS + cur];
      tags[t] = (unsigned char)cur;
    }
  }
  __syncthreads();
  out[(size_t)b * T_SEQ + tid] = (float)tags[tid];
  out[(size_t)b * T_SEQ + 256 + tid] = (float)tags[256 + tid];
}

// ---------------------------------------------------------------------------
extern "C" void kernel_launch(void* const* d_in, const int* in_sizes, int n_in,
                              void* d_out, int out_size, void* d_ws,
                              size_t ws_size, hipStream_t stream) {
  const float* x = (const float*)d_in[0];
  const float* kern = (const float*)d_in[1];
  const float* bias = (const float*)d_in[2];
  const float* chain = (const float*)d_in[3];
  const float* lb = (const float*)d_in[4];
  const float* rb = (const float*)d_in[5];
  float* out = (float*)d_out;
  float* logits = (float*)d_ws;  // final logits at ws base in all paths

  const size_t part = (size_t)M_ROWS * U_TAGS * sizeof(float);  // 16.8 MB
  if (ws_size >= 2 * part) {
    crf_gemm_half<<<dim3(256, 2), 256, 0, stream>>>(x, kern, logits);
    crf_combine<<<(M_ROWS * U_TAGS / 4 + 255) / 256, 256, 0, stream>>>(
        logits, bias, lb, rb);
  } else {
    crf_gemm<<<256, 256, 0, stream>>>(x, kern, bias, lb, rb, logits);
  }
  crf_viterbi<<<64, 256, 0, stream>>>(logits, chain, out);
}